// Round 3
// 3957.488 us; speedup vs baseline: 2.1544x; 2.1544x over previous
//
#include <hip/hip_runtime.h>
#include <math.h>

#define B_    1000
#define N_    20
#define D_    172
#define DE_   172
#define DT_   100
#define E_    272
#define DK_   444
#define HD_   136
#define TPB_  448
#define NWAVE 7
#define INV_SQRT_HD 0.08574929257125442f

// ---------------------------------------------------------------------------
// Batched transpose: src[l][r][c] -> dst[l][c][r]
// ---------------------------------------------------------------------------
__global__ void transpose_batched(const float* __restrict__ src, float* __restrict__ dst,
                                  int rows, int cols) {
    int idx = blockIdx.x * blockDim.x + threadIdx.x;
    int tot = 2 * rows * cols;
    if (idx >= tot) return;
    int l = idx / (rows * cols);
    int rem = idx - l * rows * cols;
    int r = rem / cols, c = rem - r * cols;
    dst[(size_t)l * rows * cols + (size_t)c * rows + r] = src[idx];
}

// ---------------------------------------------------------------------------
// Fused TGN temporal-attention layer, algebraically restructured:
//   score[h][n] = (q_h @ Wk_h) . kv[n] + q_h . bk_h      (project q, not k)
//   o[e]        = Wv[e] . (sum_n a[h(e)][n] kv[n]) + bv[e] (aggregate, then project)
// kv is never materialized in LDS: thread t owns column t of kv in registers.
// One block per query, 448 threads (7 waves).
// ---------------------------------------------------------------------------
template<int LAYER>
__global__ __launch_bounds__(TPB_, 6)
void aggregate_kernel(
    const float* __restrict__ memory,
    const float* __restrict__ edge_features,
    const int*   __restrict__ source_nodes,
    const float* __restrict__ timestamps,
    const int*   __restrict__ neighbors1,
    const int*   __restrict__ edge_idxs1,
    const float* __restrict__ edge_times1,
    const int*   __restrict__ neighbors2,
    const int*   __restrict__ edge_idxs2,
    const float* __restrict__ edge_times2,
    const float* __restrict__ w_time,
    const float* __restrict__ b_time,
    const float* __restrict__ WqT, const float* __restrict__ bq,
    const float* __restrict__ Wk,  const float* __restrict__ bk,   // Wk in ORIGINAL [E][DK] layout
    const float* __restrict__ WvT, const float* __restrict__ bv,
    const float* __restrict__ WoT, const float* __restrict__ bo,
    const float* __restrict__ W1T, const float* __restrict__ b1,
    const float* __restrict__ W2T, const float* __restrict__ b2,
    const float* __restrict__ emb1_in,
    float* __restrict__ outp)
{
    __shared__ float xq[E_];          // [src || cos(b_time)], reused as o[] later
    __shared__ float qv[E_];          // q
    __shared__ float sf[D_];          // source features
    __shared__ float ctx[2][DK_];     // attention-aggregated kv per head
    __shared__ float x1[DK_];         // [o' || src]
    __shared__ float h1[D_];          // relu hidden
    __shared__ float part[NWAVE][2][N_]; // per-wave score partials
    __shared__ float qbw[NWAVE][2];   // per-wave q.bk partials
    __shared__ float sc[2][N_];
    __shared__ float aw[2][N_];

    const int g = blockIdx.x;
    const int t = threadIdx.x;
    const int lane = t & 63;
    const int wid  = t >> 6;
    const int b = (LAYER == 0) ? (g / N_) : g;
    const float ts = timestamps[b];

    int src_node;
    const int*   nbrs;
    const int*   eidx;
    const float* etim;
    if (LAYER == 0) {
        src_node = neighbors1[g];
        nbrs = neighbors2  + (size_t)g * N_;
        eidx = edge_idxs2  + (size_t)g * N_;
        etim = edge_times2 + (size_t)g * N_;
    } else {
        src_node = source_nodes[b];
        nbrs = neighbors1  + (size_t)b * N_;
        eidx = edge_idxs1  + (size_t)b * N_;
        etim = edge_times1 + (size_t)b * N_;
    }

    // ---- stage: thread t holds kv column t (20 values) in registers ----
    float kvreg[N_];
    if (t < D_) {
        if (LAYER == 0) {
            #pragma unroll
            for (int n = 0; n < N_; ++n) kvreg[n] = memory[(size_t)nbrs[n] * D_ + t];
        } else {
            const float* base = emb1_in + ((size_t)b * N_) * D_ + t;
            #pragma unroll
            for (int n = 0; n < N_; ++n) kvreg[n] = base[(size_t)n * D_];
        }
        float v = memory[(size_t)src_node * D_ + t];
        sf[t] = v; xq[t] = v;
    } else if (t < E_) {
        const int j = t - D_;
        const float wt = w_time[j], bt = b_time[j];
        #pragma unroll
        for (int n = 0; n < N_; ++n) kvreg[n] = cosf((ts - etim[n]) * wt + bt);
        xq[t] = cosf(bt);            // time_enc(0)
    } else if (t < DK_) {
        const int i = t - E_;
        #pragma unroll
        for (int n = 0; n < N_; ++n) kvreg[n] = edge_features[(size_t)eidx[n] * DE_ + i];
    } else {
        #pragma unroll
        for (int n = 0; n < N_; ++n) kvreg[n] = 0.f;
    }
    __syncthreads();

    // ---- q = xq @ Wq^T + bq; per-wave partials of q_h . bk_h ----
    float pb0 = 0.f, pb1 = 0.f;
    if (t < E_) {
        float acc = bq[t];
        for (int i0 = 0; i0 < E_; i0 += 16) {      // 272 = 17*16
            float w[16], x[16];
            #pragma unroll
            for (int u = 0; u < 16; ++u) { w[u] = WqT[(size_t)(i0+u)*E_ + t]; x[u] = xq[i0+u]; }
            #pragma unroll
            for (int u = 0; u < 16; ++u) acc += x[u] * w[u];
        }
        qv[t] = acc;
        const float qb = acc * bk[t];
        if (t < HD_) pb0 = qb; else pb1 = qb;
    }
    #pragma unroll
    for (int s = 32; s; s >>= 1) { pb0 += __shfl_xor(pb0, s, 64); pb1 += __shfl_xor(pb1, s, 64); }
    if (lane == 0) { qbw[wid][0] = pb0; qbw[wid][1] = pb1; }
    __syncthreads();

    // ---- qkh[h][t] = sum_{e in head h} q[e] * Wk[e][t] (register-resident) ----
    float qk0 = 0.f, qk1 = 0.f;
    if (t < DK_) {
        const float* Wk0 = Wk + t;
        for (int e0 = 0; e0 < HD_; e0 += 8) {       // 136 = 17*8
            float w[8], q8[8];
            #pragma unroll
            for (int u = 0; u < 8; ++u) { w[u] = Wk0[(size_t)(e0+u)*DK_]; q8[u] = qv[e0+u]; }
            #pragma unroll
            for (int u = 0; u < 8; ++u) qk0 += q8[u] * w[u];
        }
        for (int e0 = HD_; e0 < E_; e0 += 8) {
            float w[8], q8[8];
            #pragma unroll
            for (int u = 0; u < 8; ++u) { w[u] = Wk0[(size_t)(e0+u)*DK_]; q8[u] = qv[e0+u]; }
            #pragma unroll
            for (int u = 0; u < 8; ++u) qk1 += q8[u] * w[u];
        }
    }

    // ---- score partials: reduce qkh[h][t]*kv[n][t] over t via shuffles ----
    for (int n0 = 0; n0 < N_; n0 += 4) {
        float p[8];
        #pragma unroll
        for (int j = 0; j < 4; ++j) { p[2*j] = qk0 * kvreg[n0+j]; p[2*j+1] = qk1 * kvreg[n0+j]; }
        #pragma unroll
        for (int j = 0; j < 8; ++j) {
            #pragma unroll
            for (int s = 32; s; s >>= 1) p[j] += __shfl_xor(p[j], s, 64);
        }
        if (lane == 0) {
            #pragma unroll
            for (int j = 0; j < 4; ++j) { part[wid][0][n0+j] = p[2*j]; part[wid][1][n0+j] = p[2*j+1]; }
        }
    }
    __syncthreads();

    // ---- combine wave partials -> scores ----
    if (t < 2 * N_) {
        const int h = t / N_, n = t - (t / N_) * N_;
        float s = 0.f, qb = 0.f;
        #pragma unroll
        for (int w = 0; w < NWAVE; ++w) { s += part[w][h][n]; qb += qbw[w][h]; }
        s = (s + qb) * INV_SQRT_HD;
        if (nbrs[n] == 0) s = -1e9f;
        sc[h][n] = s;
    }
    __syncthreads();

    // ---- softmax over 20 neighbors, per head ----
    if (t < 2) {
        float m = -INFINITY;
        #pragma unroll
        for (int n = 0; n < N_; ++n) m = fmaxf(m, sc[t][n]);
        float ex[N_], ssum = 0.f;
        #pragma unroll
        for (int n = 0; n < N_; ++n) { ex[n] = expf(sc[t][n] - m); ssum += ex[n]; }
        const float inv = 1.f / ssum;
        #pragma unroll
        for (int n = 0; n < N_; ++n) aw[t][n] = ex[n] * inv;
    }
    __syncthreads();

    // ---- ctx[h][t] = sum_n a[h][n] * kv[n][t] ----
    if (t < DK_) {
        float c0 = 0.f, c1 = 0.f;
        #pragma unroll
        for (int n = 0; n < N_; ++n) { c0 += aw[0][n] * kvreg[n]; c1 += aw[1][n] * kvreg[n]; }
        ctx[0][t] = c0; ctx[1][t] = c1;
    }
    if (t < D_) x1[E_ + t] = sf[t];
    __syncthreads();

    // ---- o[e] = ctx[h(e)] @ WvT + bv (sum(a)=1 absorbs bv), into xq ----
    if (t < E_) {
        const float* ch = ctx[t / HD_];
        float acc = bv[t];
        for (int i0 = 0; i0 < DK_; i0 += 12) {      // 444 = 37*12
            float w[12], x[12];
            #pragma unroll
            for (int u = 0; u < 12; ++u) { w[u] = WvT[(size_t)(i0+u)*E_ + t]; x[u] = ch[i0+u]; }
            #pragma unroll
            for (int u = 0; u < 12; ++u) acc += x[u] * w[u];
        }
        xq[t] = acc;
    }
    __syncthreads();

    // ---- o' = o @ Wo^T + bo; zero if fully masked ----
    if (t < E_) {
        float acc = bo[t];
        for (int i0 = 0; i0 < E_; i0 += 16) {
            float w[16], x[16];
            #pragma unroll
            for (int u = 0; u < 16; ++u) { w[u] = WoT[(size_t)(i0+u)*E_ + t]; x[u] = xq[i0+u]; }
            #pragma unroll
            for (int u = 0; u < 16; ++u) acc += x[u] * w[u];
        }
        int am = 1;
        #pragma unroll
        for (int n = 0; n < N_; ++n) am &= (nbrs[n] == 0);
        x1[t] = am ? 0.f : acc;
    }
    __syncthreads();

    // ---- MLP: h = relu([o'||src] @ W1^T + b1) ----
    if (t < D_) {
        float acc = b1[t];
        for (int i0 = 0; i0 < DK_; i0 += 12) {
            float w[12], x[12];
            #pragma unroll
            for (int u = 0; u < 12; ++u) { w[u] = W1T[(size_t)(i0+u)*D_ + t]; x[u] = x1[i0+u]; }
            #pragma unroll
            for (int u = 0; u < 12; ++u) acc += x[u] * w[u];
        }
        h1[t] = fmaxf(acc, 0.f);
    }
    __syncthreads();

    // ---- out = h @ W2^T + b2 ----
    if (t < D_) {
        float acc = b2[t];
        for (int i0 = 0; i0 < D_; i0 += 4) {        // 172 = 43*4
            float w[4], x[4];
            #pragma unroll
            for (int u = 0; u < 4; ++u) { w[u] = W2T[(size_t)(i0+u)*D_ + t]; x[u] = h1[i0+u]; }
            #pragma unroll
            for (int u = 0; u < 4; ++u) acc += x[u] * w[u];
        }
        outp[(size_t)g * D_ + t] = acc;
    }
}

// ---------------------------------------------------------------------------
extern "C" void kernel_launch(void* const* d_in, const int* in_sizes, int n_in,
                              void* d_out, int out_size, void* d_ws, size_t ws_size,
                              hipStream_t stream) {
    const float* memory        = (const float*)d_in[0];
    const float* edge_features = (const float*)d_in[1];
    const int*   source_nodes  = (const int*)  d_in[2];
    const float* timestamps    = (const float*)d_in[3];
    const int*   neighbors1    = (const int*)  d_in[4];
    const int*   edge_idxs1    = (const int*)  d_in[5];
    const float* edge_times1   = (const float*)d_in[6];
    const int*   neighbors2    = (const int*)  d_in[7];
    const int*   edge_idxs2    = (const int*)  d_in[8];
    const float* edge_times2   = (const float*)d_in[9];
    const float* w_time        = (const float*)d_in[10];
    const float* b_time        = (const float*)d_in[11];
    const float* Wq = (const float*)d_in[12];
    const float* bq = (const float*)d_in[13];
    const float* Wk = (const float*)d_in[14];
    const float* bk = (const float*)d_in[15];
    const float* Wv = (const float*)d_in[16];
    const float* bv = (const float*)d_in[17];
    const float* Wo = (const float*)d_in[18];
    const float* bo = (const float*)d_in[19];
    const float* W1 = (const float*)d_in[20];
    const float* b1 = (const float*)d_in[21];
    const float* W2 = (const float*)d_in[22];
    const float* b2 = (const float*)d_in[23];

    float* ws = (float*)d_ws;
    size_t off = 0;
    float* WqT = ws + off; off += (size_t)2 * E_  * E_;
    float* WvT = ws + off; off += (size_t)2 * DK_ * E_;
    float* WoT = ws + off; off += (size_t)2 * E_  * E_;
    float* W1T = ws + off; off += (size_t)2 * DK_ * D_;
    float* W2T = ws + off; off += (size_t)2 * D_  * D_;
    float* emb1 = ws + off; off += (size_t)(B_ * N_) * D_;   // 20000 x 172

    auto tp = [&](const float* src, float* dst, int rows, int cols) {
        int tot = 2 * rows * cols;
        transpose_batched<<<(tot + 255) / 256, 256, 0, stream>>>(src, dst, rows, cols);
    };
    tp(Wq, WqT, E_, E_);
    tp(Wv, WvT, E_, DK_);
    tp(Wo, WoT, E_, E_);
    tp(W1, W1T, D_, DK_);
    tp(W2, W2T, D_, D_);
    // Wk stays in original [E][DK] layout (qkh phase reads it coalesced over i).

    // Layer 1 (l=0): 20000 queries -> emb1
    aggregate_kernel<0><<<B_ * N_, TPB_, 0, stream>>>(
        memory, edge_features, source_nodes, timestamps,
        neighbors1, edge_idxs1, edge_times1,
        neighbors2, edge_idxs2, edge_times2,
        w_time, b_time,
        WqT, bq, Wk, bk, WvT, bv, WoT, bo, W1T, b1, W2T, b2,
        nullptr, emb1);

    // Layer 2 (l=1): 1000 queries -> d_out
    aggregate_kernel<1><<<B_, TPB_, 0, stream>>>(
        memory, edge_features, source_nodes, timestamps,
        neighbors1, edge_idxs1, edge_times1,
        neighbors2, edge_idxs2, edge_times2,
        w_time, b_time,
        WqT + E_ * E_,  bq + E_,
        Wk  + E_ * DK_, bk + E_,
        WvT + DK_ * E_, bv + E_,
        WoT + E_ * E_,  bo + E_,
        W1T + DK_ * D_, b1 + D_,
        W2T + D_ * D_,  b2 + D_,
        emb1, (float*)d_out);
}